// Round 9
// baseline (497.979 us; speedup 1.0000x reference)
//
#include <hip/hip_runtime.h>
#include <stdint.h>

typedef short bf16x8 __attribute__((ext_vector_type(8)));
typedef unsigned short u16x8 __attribute__((ext_vector_type(8)));
typedef float f32x4 __attribute__((ext_vector_type(4)));

#define NPB 512          // nodes per bucket
#define BSHIFT 9
#define MAXBUCK 256      // supports N <= 131072
#define STAGE_CAP 12288  // per-bucket csr staging (mean 8163, sigma ~90)
#define LROW 136         // LDS mean row stride in shorts (272 B)

__device__ __forceinline__ short f2bf(float f) {
    uint32_t u = __float_as_uint(f);
    u += 0x7fffu + ((u >> 16) & 1u);   // round-to-nearest-even
    return (short)(u >> 16);
}
__device__ __forceinline__ float bf2f(unsigned short s) {
    return __uint_as_float((uint32_t)s << 16);
}

// ---- device-scope grid barrier (one-shot counter per phase) ----
// Safe: G = 196 blocks <= 256 CUs at 1 block/CU -> all co-resident.
// Writer side: __threadfence flushes L2 (device scope) before signal;
// reader side: __threadfence after release invalidates stale clean lines.
__device__ __forceinline__ void gbar(int* bar, int idx, int G) {
    __syncthreads();
    if (threadIdx.x == 0) {
        __threadfence();
        atomicAdd(&bar[idx], 1);
        while (atomicAdd(&bar[idx], 0) < G) __builtin_amdgcn_s_sleep(8);
    }
    __syncthreads();
    __threadfence();
}

// ---- whole CSR-build chain + conversions in ONE kernel ----
// Phase A: convx || convw4 || LDS-agg bucket histogram (grid-strided)
// Phase B: 512-wide scan over bucket counts (block 0)
// Phase C: bin edges into bucket regions (R8 bin body, window per block)
// Phase D: per-bucket build -> rowptr + coalesced csr (R8 build body)
__global__ __launch_bounds__(512) void chain_kernel(
    const float* __restrict__ x, short* __restrict__ xb, int nx,
    const float* __restrict__ w0, const float* __restrict__ w1,
    const float* __restrict__ w2, const float* __restrict__ w3,
    short* __restrict__ o0, short* __restrict__ o1,
    short* __restrict__ o2, short* __restrict__ o3,
    const int* __restrict__ src, const int* __restrict__ dst,
    int* __restrict__ bcnt, int* __restrict__ bbase,
    int* __restrict__ gcur, int* __restrict__ bar,
    unsigned int* __restrict__ binned,
    int* __restrict__ rowptr, int* __restrict__ csr,
    int E, int N, int B, int G, int win)
{
    __shared__ int sh[3 * NPB + STAGE_CAP];   // 13824 ints = 55296 B
    const int t = threadIdx.x;
    const int g = blockIdx.x;
    const int stride = G * 512;

    // ================= phase A =================
    {
        int* h = sh;                          // B <= 256 counters
        for (int i = t; i < B; i += 512) h[i] = 0;
        __syncthreads();
        // convw4: 4 x 16384 elems
        for (int i = g * 512 + t; i < 16384; i += stride) {
            o0[i] = f2bf(w0[i]);
            o1[i] = f2bf(w1[i]);
            o2[i] = f2bf(w2[i]);
            o3[i] = f2bf(w3[i]);
        }
        // convx: 8 elems/thread/iter (nx = N*128, multiple of 8)
        const int ncx = nx >> 3;
        for (int i = g * 512 + t; i < ncx; i += stride) {
            const int j = i << 3;
            const float4 v0 = *(const float4*)(x + j);
            const float4 v1 = *(const float4*)(x + j + 4);
            bf16x8 o;
            o[0] = f2bf(v0.x); o[1] = f2bf(v0.y); o[2] = f2bf(v0.z); o[3] = f2bf(v0.w);
            o[4] = f2bf(v1.x); o[5] = f2bf(v1.y); o[6] = f2bf(v1.z); o[7] = f2bf(v1.w);
            *(bf16x8*)(xb + j) = o;
        }
        // bucket histogram (LDS-aggregated)
        for (int e = g * 512 + t; e < E; e += stride)
            atomicAdd(&h[dst[e] >> BSHIFT], 1);
        __syncthreads();
        for (int i = t; i < B; i += 512)
            if (h[i]) atomicAdd(&bcnt[i], h[i]);
    }
    gbar(bar, 0, G);

    // ================= phase B: scan (block 0) =================
    if (g == 0) {
        int* s = sh;
        const int v = (t < B) ? atomicAdd(&bcnt[t], 0) : 0;   // coherent read
        s[t] = v;
        __syncthreads();
        for (int off = 1; off < 512; off <<= 1) {
            int a = (t >= off) ? s[t - off] : 0;
            __syncthreads();
            s[t] += a;
            __syncthreads();
        }
        const int excl = s[t] - v;
        if (t < B) { bbase[t] = excl; gcur[t] = excl; }
        if (t == B - 1) bbase[B] = excl + v;
        if (t == 0) rowptr[N] = E;
    }
    gbar(bar, 1, G);

    // ================= phase C: bin (window per block) =================
    {
        int* cnt  = sh;
        int* base = sh + MAXBUCK;
        for (int i = t; i < B; i += 512) cnt[i] = 0;
        __syncthreads();
        const int e0 = g * win;
        const int eEnd = (e0 + win < E) ? (e0 + win) : E;
#pragma unroll 4
        for (int e = e0 + t; e < eEnd; e += 512)
            atomicAdd(&cnt[dst[e] >> BSHIFT], 1);
        __syncthreads();
        for (int i = t; i < B; i += 512) {
            int c = cnt[i];
            base[i] = c ? atomicAdd(&gcur[i], c) : 0;
            cnt[i] = 0;   // reuse as local cursor
        }
        __syncthreads();
#pragma unroll 4
        for (int e = e0 + t; e < eEnd; e += 512) {
            int sv = src[e], dv = dst[e];
            int b = dv >> BSHIFT;
            int off = atomicAdd(&cnt[b], 1);
            binned[base[b] + off] = ((unsigned)sv << BSHIFT) | (unsigned)(dv & (NPB - 1));
        }
    }
    gbar(bar, 2, G);

    // ================= phase D: build (bucket per block) =================
    if (g < B) {
        int* hist  = sh;
        int* cur   = sh + NPB;
        int* scanb = sh + 2 * NPB;
        int* stage = sh + 3 * NPB;
        const int cbeg = bbase[g], cend = bbase[g + 1];
        const int cnt = cend - cbeg;
        hist[t] = 0;
        __syncthreads();
        for (int i = t; i < cnt; i += 512)
            atomicAdd(&hist[binned[cbeg + i] & (NPB - 1)], 1);
        __syncthreads();
        const int ps = hist[t];
        scanb[t] = ps;
        __syncthreads();
        for (int off = 1; off < 512; off <<= 1) {
            int a = (t >= off) ? scanb[t - off] : 0;
            __syncthreads();
            scanb[t] += a;
            __syncthreads();
        }
        const int e0 = scanb[t] - ps;   // exclusive prefix over 512 nodes
        cur[t] = e0;
        const int node = (g << BSHIFT) + t;
        if (node < N) rowptr[node] = cbeg + e0;
        __syncthreads();
        for (int i = t; i < cnt; i += 512) {
            unsigned rec = binned[cbeg + i];
            int ld  = rec & (NPB - 1);
            int pos = atomicAdd(&cur[ld], 1);
            if (pos < STAGE_CAP) stage[pos] = (int)(rec >> BSHIFT);
            else                 csr[cbeg + pos] = (int)(rec >> BSHIFT);
        }
        __syncthreads();
        const int lim = cnt < STAGE_CAP ? cnt : STAGE_CAP;
        for (int i = t; i < lim; i += 512)
            csr[cbeg + i] = stage[i];
    }
    // kernel end: visibility to fused kernels via stream ordering
}

// ---- fused layer: out = [relu]( mean(feat) @ Wl^T + b + feat @ Wr^T ) ----
// R3 geometry (measured 124.4 us, 44 VGPR, 45% occ — best of 4 variants):
// block = 4 waves = 32 nodes; quarter-wave owns 2 nodes; phase 2 splits each
// 16-row MFMA tile across 2 waves (4 column-tiles each); one __syncthreads.
#define ACC8(u) do { \
    a0 += bf2f(u[0]); a1 += bf2f(u[1]); a2 += bf2f(u[2]); a3 += bf2f(u[3]); \
    a4 += bf2f(u[4]); a5 += bf2f(u[5]); a6 += bf2f(u[6]); a7 += bf2f(u[7]); } while (0)

template <bool RELU>
__global__ __launch_bounds__(256) void fused_kernel(
    const short* __restrict__ feat, const int* __restrict__ csr,
    const int* __restrict__ rowptr,
    const short* __restrict__ Wl, const short* __restrict__ Wr,
    const float* __restrict__ bias,
    short* __restrict__ outb, float* __restrict__ outf, int N)
{
    __shared__ short lmean[32 * LROW];
    const int lane = threadIdx.x & 63;
    const int wave = threadIdx.x >> 6;
    const int q    = lane >> 4;          // quarter
    const int ql   = lane & 15;          // lane in quarter
    const int nb0  = blockIdx.x * 32;    // block's first node
    const int m0w  = nb0 + wave * 8;     // wave's first node (phase 1)

    // ---- phase 1: aggregate; quarter q owns node m0w + it*4 + q (it=0,1)
    for (int it = 0; it < 2; ++it) {
        const int node = m0w + it * 4 + q;
        const int lrow = wave * 8 + it * 4 + q;
        float a0=0,a1=0,a2=0,a3=0,a4=0,a5=0,a6=0,a7=0;
        if (node < N) {
            const int beg = rowptr[node], end = rowptr[node + 1];
            int e = beg;
            for (; e + 4 <= end; e += 4) {
                const int s0 = csr[e], s1 = csr[e+1], s2 = csr[e+2], s3 = csr[e+3];
                const u16x8 u0 = *(const u16x8*)(feat + (size_t)s0 * 128 + ql * 8);
                const u16x8 u1 = *(const u16x8*)(feat + (size_t)s1 * 128 + ql * 8);
                const u16x8 u2 = *(const u16x8*)(feat + (size_t)s2 * 128 + ql * 8);
                const u16x8 u3 = *(const u16x8*)(feat + (size_t)s3 * 128 + ql * 8);
                ACC8(u0); ACC8(u1); ACC8(u2); ACC8(u3);
            }
            for (; e < end; ++e) {
                const u16x8 u = *(const u16x8*)(feat + (size_t)csr[e] * 128 + ql * 8);
                ACC8(u);
            }
            const float r = 1.0f / fmaxf((float)(end - beg), 1.0f);
            bf16x8 o;
            o[0] = f2bf(a0 * r); o[1] = f2bf(a1 * r); o[2] = f2bf(a2 * r); o[3] = f2bf(a3 * r);
            o[4] = f2bf(a4 * r); o[5] = f2bf(a5 * r); o[6] = f2bf(a6 * r); o[7] = f2bf(a7 * r);
            *(bf16x8*)(lmean + (size_t)lrow * LROW + ql * 8) = o;
        } else {
            *(bf16x8*)(lmean + (size_t)lrow * LROW + ql * 8) = (bf16x8)0;
        }
    }
    __syncthreads();   // phase 2 reads lmean rows written by a sibling wave

    // ---- phase 2: wave -> (row-tile t2 = wave>>1, col-half h = wave&1)
    const int t2 = wave >> 1;
    const int h  = wave & 1;
    const int m0 = nb0 + t2 * 16;        // tile's first node row
    f32x4 acc[4];
#pragma unroll
    for (int i = 0; i < 4; ++i) acc[i] = (f32x4)0.0f;
    const bool valid = (m0 + ql < N);

#pragma unroll
    for (int kk = 0; kk < 4; ++kk) {
        const int kb = kk * 32 + q * 8;
        const bf16x8 a = *(const bf16x8*)(lmean + (size_t)(t2 * 16 + ql) * LROW + kb);
#pragma unroll
        for (int nt = 0; nt < 4; ++nt) {
            const bf16x8 b = *(const bf16x8*)(Wl + (size_t)(h * 64 + nt * 16 + ql) * 128 + kb);
            acc[nt] = __builtin_amdgcn_mfma_f32_16x16x32_bf16(a, b, acc[nt], 0, 0, 0);
        }
    }
#pragma unroll
    for (int kk = 0; kk < 4; ++kk) {
        const int kb = kk * 32 + q * 8;
        bf16x8 a = (bf16x8)0;
        if (valid) a = *(const bf16x8*)(feat + (size_t)(m0 + ql) * 128 + kb);
#pragma unroll
        for (int nt = 0; nt < 4; ++nt) {
            const bf16x8 b = *(const bf16x8*)(Wr + (size_t)(h * 64 + nt * 16 + ql) * 128 + kb);
            acc[nt] = __builtin_amdgcn_mfma_f32_16x16x32_bf16(a, b, acc[nt], 0, 0, 0);
        }
    }

    const int rbase = m0 + q * 4;
#pragma unroll
    for (int nt = 0; nt < 4; ++nt) {
        const int col = h * 64 + nt * 16 + ql;
        const float bc = bias[col];
#pragma unroll
        for (int r = 0; r < 4; ++r) {
            const int node = rbase + r;
            if (node < N) {
                float v = acc[nt][r] + bc;
                if (RELU) outb[(size_t)node * 128 + col] = f2bf(fmaxf(v, 0.0f));
                else      outf[(size_t)node * 128 + col] = v;
            }
        }
    }
}

extern "C" void kernel_launch(void* const* d_in, const int* in_sizes, int n_in,
                              void* d_out, int out_size, void* d_ws, size_t ws_size,
                              hipStream_t stream) {
    const float* x   = (const float*)d_in[0];
    const int*   ei  = (const int*)d_in[1];
    const float* Wl1 = (const float*)d_in[2];
    const float* bl1 = (const float*)d_in[3];
    const float* Wr1 = (const float*)d_in[4];
    const float* Wl2 = (const float*)d_in[5];
    const float* bl2 = (const float*)d_in[6];
    const float* Wr2 = (const float*)d_in[7];

    const int N = in_sizes[0] / 128;
    const int E = in_sizes[1] / 2;
    const int* src = ei;
    const int* dst = ei + E;
    const int B = (N + NPB - 1) >> BSHIFT;   // 196 for N=100000

    // ws: h_bf16 | 4x bf16 weights | rowptr | csr | binned | meta (128B-aligned regions)
    char* wsb = (char*)d_ws;
    short* hbuf = (short*)wsb;                                  // N*128 bf16
    size_t off = (size_t)N * 128 * 2;
    short* wl1 = (short*)(wsb + off); off += 16384 * 2;
    short* wr1 = (short*)(wsb + off); off += 16384 * 2;
    short* wl2 = (short*)(wsb + off); off += 16384 * 2;
    short* wr2 = (short*)(wsb + off); off += 16384 * 2;
    int* rowptr = (int*)(wsb + off);                            // N+1
    off += ((size_t)(N + 1) * 4 + 127) & ~(size_t)127;
    int* csr = (int*)(wsb + off);                               // E
    off += ((size_t)E * 4 + 127) & ~(size_t)127;
    unsigned int* binned = (unsigned int*)(wsb + off);          // E
    off += ((size_t)E * 4 + 127) & ~(size_t)127;
    int* bcnt  = (int*)(wsb + off);                             // 288 ints (257 used)
    int* bbase = bcnt + 288;                                    // 288 ints (257 used)
    int* gcur  = bbase + 288;                                   // 256 ints
    int* bar   = gcur + 256;                                    // 32 ints (4 used)

    // d_out: xb (bf16 x) at base — read only by fused1, overwritten by fused2's out
    short* xb  = (short*)d_out;
    float* out = (float*)d_out;

    const int nx = N * 128;
    const int G  = B;                        // 196 blocks, 1/CU — co-resident
    const int win = (E + G - 1) / G;         // ~8164 edges per bin window
    const int fusedBlocks = (N + 31) / 32;

    // zero bcnt + bar (+ bbase/gcur harmlessly) — re-runs every graph replay
    (void)hipMemsetAsync(bcnt, 0, (size_t)(288 + 288 + 256 + 32) * sizeof(int), stream);

    chain_kernel<<<G, 512, 0, stream>>>(
        x, xb, nx, Wl1, Wr1, Wl2, Wr2, wl1, wr1, wl2, wr2,
        src, dst, bcnt, bbase, gcur, bar, binned, rowptr, csr,
        E, N, B, G, win);

    // layer 1: feat = xb (d_out), out = hbuf (ws)
    fused_kernel<true><<<fusedBlocks, 256, 0, stream>>>(xb, csr, rowptr, wl1, wr1, bl1,
                                                        hbuf, (float*)nullptr, N);
    // layer 2: feat = hbuf (ws), out = d_out (overwrites xb region; safe)
    fused_kernel<false><<<fusedBlocks, 256, 0, stream>>>(hbuf, csr, rowptr, wl2, wr2, bl2,
                                                         (short*)nullptr, out, N);
}

// Round 10
// 457.711 us; speedup vs baseline: 1.0880x; 1.0880x over previous
//
#include <hip/hip_runtime.h>
#include <stdint.h>

typedef short bf16x8 __attribute__((ext_vector_type(8)));
typedef unsigned short u16x8 __attribute__((ext_vector_type(8)));
typedef float f32x4 __attribute__((ext_vector_type(4)));

#define NPB 512          // nodes per bucket
#define BSHIFT 9
#define MAXBUCK 256      // supports N <= 131072
#define STAGE_CAP 12288  // per-bucket csr staging (mean 8163, sigma ~90)
#define LROW 136         // LDS mean row stride in shorts (272 B)

__device__ __forceinline__ short f2bf(float f) {
    uint32_t u = __float_as_uint(f);
    u += 0x7fffu + ((u >> 16) & 1u);   // round-to-nearest-even
    return (short)(u >> 16);
}
__device__ __forceinline__ float bf2f(unsigned short s) {
    return __uint_as_float((uint32_t)s << 16);
}

// ---- device-scope grid barrier, LOAD-polling (R9 lesson: RMW-poll from 196
// blocks serializes cross-XCD, ~35us/barrier; atomic loads don't serialize).
// Safe: G = 196 blocks, 55KB LDS -> 2 blocks/CU capacity, all co-resident.
// Fencing pattern (threadfence + atomic signal) correctness-validated in R9.
__device__ __forceinline__ void gbar(int* bar, int idx, int G) {
    __syncthreads();
    if (threadIdx.x == 0) {
        __threadfence();
        atomicAdd(&bar[idx], 1);
        while (__hip_atomic_load(&bar[idx], __ATOMIC_RELAXED,
                                 __HIP_MEMORY_SCOPE_AGENT) < G)
            __builtin_amdgcn_s_sleep(4);
    }
    __syncthreads();
    __threadfence();
}

// ---- CSR chain in one kernel, 2 barriers ----
// A: bucket histogram (grid-strided, LDS-agg) -> bcnt     [barrier]
// B: EVERY block locally scans bcnt (196 ints, redundant) -> sbase in LDS,
//    own cbeg/cend in regs (no broadcast barrier needed)
// C: bin window -> binned; base = sbase[b] + atomicAdd(gcur0[b]) [barrier]
// D: build bucket g -> rowptr + coalesced csr
// tail: convx + convw4 (independent; kernel-end orders before fused1)
__global__ __launch_bounds__(512) void chain_kernel(
    const float* __restrict__ x, short* __restrict__ xb, int nx,
    const float* __restrict__ w0, const float* __restrict__ w1,
    const float* __restrict__ w2, const float* __restrict__ w3,
    short* __restrict__ o0, short* __restrict__ o1,
    short* __restrict__ o2, short* __restrict__ o3,
    const int* __restrict__ src, const int* __restrict__ dst,
    int* __restrict__ bcnt, int* __restrict__ gcur, int* __restrict__ bar,
    unsigned int* __restrict__ binned,
    int* __restrict__ rowptr, int* __restrict__ csr,
    int E, int N, int B, int G, int win)
{
    __shared__ int sh[1536 + STAGE_CAP];   // 13824 ints = 55296 B
    const int t = threadIdx.x;
    const int g = blockIdx.x;

    // ================= phase A: bucket histogram =================
    {
        int* h = sh;                          // [0..255]
        for (int i = t; i < B; i += 512) h[i] = 0;
        __syncthreads();
        const int stride = G * 512;
        for (int e = g * 512 + t; e < E; e += stride)
            atomicAdd(&h[dst[e] >> BSHIFT], 1);
        __syncthreads();
        for (int i = t; i < B; i += 512)
            if (h[i]) atomicAdd(&bcnt[i], h[i]);
    }
    gbar(bar, 0, G);

    // ================= phase B: redundant local scan =================
    int cbeg = 0, cend = 0;
    {
        const int v = (t < B) ? __hip_atomic_load(&bcnt[t], __ATOMIC_RELAXED,
                                                  __HIP_MEMORY_SCOPE_AGENT) : 0;
        int* ws = sh + 256;                   // [256..767]
        ws[t] = v;
        __syncthreads();
        for (int off = 1; off < 512; off <<= 1) {
            int a = (t >= off) ? ws[t - off] : 0;
            __syncthreads();
            ws[t] += a;
            __syncthreads();
        }
        if (t < B) sh[t] = ws[t] - v;         // sbase[t], [0..255]
        if (t == B - 1) sh[B] = ws[t];        // total = E
        __syncthreads();
        if (g < B) { cbeg = sh[g]; cend = sh[g + 1]; }   // saved to regs
    }

    // ================= phase C: bin (window per block) =================
    {
        int* cnt  = sh + 768;                 // [768..1023]
        int* base = sh + 1024;                // [1024..1279]
        for (int i = t; i < B; i += 512) cnt[i] = 0;
        __syncthreads();
        const int e0 = g * win;
        const int eEnd = (e0 + win < E) ? (e0 + win) : E;
#pragma unroll 4
        for (int e = e0 + t; e < eEnd; e += 512)
            atomicAdd(&cnt[dst[e] >> BSHIFT], 1);
        __syncthreads();
        for (int i = t; i < B; i += 512) {
            int c = cnt[i];
            base[i] = c ? (sh[i] + atomicAdd(&gcur[i], c)) : 0;
            cnt[i] = 0;   // reuse as local cursor
        }
        __syncthreads();
#pragma unroll 4
        for (int e = e0 + t; e < eEnd; e += 512) {
            int sv = src[e], dv = dst[e];
            int b = dv >> BSHIFT;
            int off = atomicAdd(&cnt[b], 1);
            binned[base[b] + off] = ((unsigned)sv << BSHIFT) | (unsigned)(dv & (NPB - 1));
        }
    }
    gbar(bar, 1, G);

    // ================= phase D: build (bucket per block) =================
    if (g < B) {
        int* hist  = sh;                      // [0..511]
        int* cur   = sh + 512;                // [512..1023]
        int* scanb = sh + 1024;               // [1024..1535]
        int* stage = sh + 1536;               // [1536..]
        const int cnt = cend - cbeg;
        hist[t] = 0;
        __syncthreads();
        for (int i = t; i < cnt; i += 512)
            atomicAdd(&hist[binned[cbeg + i] & (NPB - 1)], 1);
        __syncthreads();
        const int ps = hist[t];
        scanb[t] = ps;
        __syncthreads();
        for (int off = 1; off < 512; off <<= 1) {
            int a = (t >= off) ? scanb[t - off] : 0;
            __syncthreads();
            scanb[t] += a;
            __syncthreads();
        }
        const int e0 = scanb[t] - ps;   // exclusive prefix over 512 nodes
        cur[t] = e0;
        const int node = (g << BSHIFT) + t;
        if (node < N) rowptr[node] = cbeg + e0;
        if (g == 0 && t == 0) rowptr[N] = E;
        __syncthreads();
        for (int i = t; i < cnt; i += 512) {
            unsigned rec = binned[cbeg + i];
            int ld  = rec & (NPB - 1);
            int pos = atomicAdd(&cur[ld], 1);
            if (pos < STAGE_CAP) stage[pos] = (int)(rec >> BSHIFT);
            else                 csr[cbeg + pos] = (int)(rec >> BSHIFT);
        }
        __syncthreads();
        const int lim = cnt < STAGE_CAP ? cnt : STAGE_CAP;
        for (int i = t; i < lim; i += 512)
            csr[cbeg + i] = stage[i];
    }

    // ================= tail: convx + convw4 (no barrier) =================
    {
        const int stride = G * 512;
        for (int i = g * 512 + t; i < 16384; i += stride) {
            o0[i] = f2bf(w0[i]);
            o1[i] = f2bf(w1[i]);
            o2[i] = f2bf(w2[i]);
            o3[i] = f2bf(w3[i]);
        }
        const int ncx = nx >> 3;
        for (int i = g * 512 + t; i < ncx; i += stride) {
            const int j = i << 3;
            const float4 v0 = *(const float4*)(x + j);
            const float4 v1 = *(const float4*)(x + j + 4);
            bf16x8 o;
            o[0] = f2bf(v0.x); o[1] = f2bf(v0.y); o[2] = f2bf(v0.z); o[3] = f2bf(v0.w);
            o[4] = f2bf(v1.x); o[5] = f2bf(v1.y); o[6] = f2bf(v1.z); o[7] = f2bf(v1.w);
            *(bf16x8*)(xb + j) = o;
        }
    }
}

// ---- fused layer: out = [relu]( mean(feat) @ Wl^T + b + feat @ Wr^T ) ----
// R3 geometry (measured 124.4 us, 44 VGPR, 45% occ — best of 4 variants):
// block = 4 waves = 32 nodes; quarter-wave owns 2 nodes; phase 2 splits each
// 16-row MFMA tile across 2 waves (4 column-tiles each); one __syncthreads.
#define ACC8(u) do { \
    a0 += bf2f(u[0]); a1 += bf2f(u[1]); a2 += bf2f(u[2]); a3 += bf2f(u[3]); \
    a4 += bf2f(u[4]); a5 += bf2f(u[5]); a6 += bf2f(u[6]); a7 += bf2f(u[7]); } while (0)

template <bool RELU>
__global__ __launch_bounds__(256) void fused_kernel(
    const short* __restrict__ feat, const int* __restrict__ csr,
    const int* __restrict__ rowptr,
    const short* __restrict__ Wl, const short* __restrict__ Wr,
    const float* __restrict__ bias,
    short* __restrict__ outb, float* __restrict__ outf, int N)
{
    __shared__ short lmean[32 * LROW];
    const int lane = threadIdx.x & 63;
    const int wave = threadIdx.x >> 6;
    const int q    = lane >> 4;          // quarter
    const int ql   = lane & 15;          // lane in quarter
    const int nb0  = blockIdx.x * 32;    // block's first node
    const int m0w  = nb0 + wave * 8;     // wave's first node (phase 1)

    // ---- phase 1: aggregate; quarter q owns node m0w + it*4 + q (it=0,1)
    for (int it = 0; it < 2; ++it) {
        const int node = m0w + it * 4 + q;
        const int lrow = wave * 8 + it * 4 + q;
        float a0=0,a1=0,a2=0,a3=0,a4=0,a5=0,a6=0,a7=0;
        if (node < N) {
            const int beg = rowptr[node], end = rowptr[node + 1];
            int e = beg;
            for (; e + 4 <= end; e += 4) {
                const int s0 = csr[e], s1 = csr[e+1], s2 = csr[e+2], s3 = csr[e+3];
                const u16x8 u0 = *(const u16x8*)(feat + (size_t)s0 * 128 + ql * 8);
                const u16x8 u1 = *(const u16x8*)(feat + (size_t)s1 * 128 + ql * 8);
                const u16x8 u2 = *(const u16x8*)(feat + (size_t)s2 * 128 + ql * 8);
                const u16x8 u3 = *(const u16x8*)(feat + (size_t)s3 * 128 + ql * 8);
                ACC8(u0); ACC8(u1); ACC8(u2); ACC8(u3);
            }
            for (; e < end; ++e) {
                const u16x8 u = *(const u16x8*)(feat + (size_t)csr[e] * 128 + ql * 8);
                ACC8(u);
            }
            const float r = 1.0f / fmaxf((float)(end - beg), 1.0f);
            bf16x8 o;
            o[0] = f2bf(a0 * r); o[1] = f2bf(a1 * r); o[2] = f2bf(a2 * r); o[3] = f2bf(a3 * r);
            o[4] = f2bf(a4 * r); o[5] = f2bf(a5 * r); o[6] = f2bf(a6 * r); o[7] = f2bf(a7 * r);
            *(bf16x8*)(lmean + (size_t)lrow * LROW + ql * 8) = o;
        } else {
            *(bf16x8*)(lmean + (size_t)lrow * LROW + ql * 8) = (bf16x8)0;
        }
    }
    __syncthreads();   // phase 2 reads lmean rows written by a sibling wave

    // ---- phase 2: wave -> (row-tile t2 = wave>>1, col-half h = wave&1)
    const int t2 = wave >> 1;
    const int h  = wave & 1;
    const int m0 = nb0 + t2 * 16;        // tile's first node row
    f32x4 acc[4];
#pragma unroll
    for (int i = 0; i < 4; ++i) acc[i] = (f32x4)0.0f;
    const bool valid = (m0 + ql < N);

#pragma unroll
    for (int kk = 0; kk < 4; ++kk) {
        const int kb = kk * 32 + q * 8;
        const bf16x8 a = *(const bf16x8*)(lmean + (size_t)(t2 * 16 + ql) * LROW + kb);
#pragma unroll
        for (int nt = 0; nt < 4; ++nt) {
            const bf16x8 b = *(const bf16x8*)(Wl + (size_t)(h * 64 + nt * 16 + ql) * 128 + kb);
            acc[nt] = __builtin_amdgcn_mfma_f32_16x16x32_bf16(a, b, acc[nt], 0, 0, 0);
        }
    }
#pragma unroll
    for (int kk = 0; kk < 4; ++kk) {
        const int kb = kk * 32 + q * 8;
        bf16x8 a = (bf16x8)0;
        if (valid) a = *(const bf16x8*)(feat + (size_t)(m0 + ql) * 128 + kb);
#pragma unroll
        for (int nt = 0; nt < 4; ++nt) {
            const bf16x8 b = *(const bf16x8*)(Wr + (size_t)(h * 64 + nt * 16 + ql) * 128 + kb);
            acc[nt] = __builtin_amdgcn_mfma_f32_16x16x32_bf16(a, b, acc[nt], 0, 0, 0);
        }
    }

    const int rbase = m0 + q * 4;
#pragma unroll
    for (int nt = 0; nt < 4; ++nt) {
        const int col = h * 64 + nt * 16 + ql;
        const float bc = bias[col];
#pragma unroll
        for (int r = 0; r < 4; ++r) {
            const int node = rbase + r;
            if (node < N) {
                float v = acc[nt][r] + bc;
                if (RELU) outb[(size_t)node * 128 + col] = f2bf(fmaxf(v, 0.0f));
                else      outf[(size_t)node * 128 + col] = v;
            }
        }
    }
}

extern "C" void kernel_launch(void* const* d_in, const int* in_sizes, int n_in,
                              void* d_out, int out_size, void* d_ws, size_t ws_size,
                              hipStream_t stream) {
    const float* x   = (const float*)d_in[0];
    const int*   ei  = (const int*)d_in[1];
    const float* Wl1 = (const float*)d_in[2];
    const float* bl1 = (const float*)d_in[3];
    const float* Wr1 = (const float*)d_in[4];
    const float* Wl2 = (const float*)d_in[5];
    const float* bl2 = (const float*)d_in[6];
    const float* Wr2 = (const float*)d_in[7];

    const int N = in_sizes[0] / 128;
    const int E = in_sizes[1] / 2;
    const int* src = ei;
    const int* dst = ei + E;
    const int B = (N + NPB - 1) >> BSHIFT;   // 196 for N=100000

    // ws: h_bf16 | 4x bf16 weights | rowptr | csr | binned | meta (128B-aligned)
    char* wsb = (char*)d_ws;
    short* hbuf = (short*)wsb;                                  // N*128 bf16
    size_t off = (size_t)N * 128 * 2;
    short* wl1 = (short*)(wsb + off); off += 16384 * 2;
    short* wr1 = (short*)(wsb + off); off += 16384 * 2;
    short* wl2 = (short*)(wsb + off); off += 16384 * 2;
    short* wr2 = (short*)(wsb + off); off += 16384 * 2;
    int* rowptr = (int*)(wsb + off);                            // N+1
    off += ((size_t)(N + 1) * 4 + 127) & ~(size_t)127;
    int* csr = (int*)(wsb + off);                               // E
    off += ((size_t)E * 4 + 127) & ~(size_t)127;
    unsigned int* binned = (unsigned int*)(wsb + off);          // E
    off += ((size_t)E * 4 + 127) & ~(size_t)127;
    int* bcnt = (int*)(wsb + off);                              // 288 ints (196 used)
    int* gcur = bcnt + 288;                                     // 256 ints
    int* bar  = gcur + 256;                                     // 32 ints (2 used)

    // d_out: xb (bf16 x) at base — read only by fused1, overwritten by fused2's out
    short* xb  = (short*)d_out;
    float* out = (float*)d_out;

    const int nx = N * 128;
    const int G  = B;                        // 196 blocks, co-resident
    const int win = (E + G - 1) / G;         // ~8164 edges per bin window
    const int fusedBlocks = (N + 31) / 32;

    // zero bcnt + gcur + bar — re-runs every graph replay
    (void)hipMemsetAsync(bcnt, 0, (size_t)(288 + 256 + 32) * sizeof(int), stream);

    chain_kernel<<<G, 512, 0, stream>>>(
        x, xb, nx, Wl1, Wr1, Wl2, Wr2, wl1, wr1, wl2, wr2,
        src, dst, bcnt, gcur, bar, binned, rowptr, csr,
        E, N, B, G, win);

    // layer 1: feat = xb (d_out), out = hbuf (ws)
    fused_kernel<true><<<fusedBlocks, 256, 0, stream>>>(xb, csr, rowptr, wl1, wr1, bl1,
                                                        hbuf, (float*)nullptr, N);
    // layer 2: feat = hbuf (ws), out = d_out (overwrites xb region; safe)
    fused_kernel<false><<<fusedBlocks, 256, 0, stream>>>(hbuf, csr, rowptr, wl2, wr2, bl2,
                                                         (short*)nullptr, out, N);
}

// Round 11
// 417.124 us; speedup vs baseline: 1.1938x; 1.0973x over previous
//
#include <hip/hip_runtime.h>
#include <stdint.h>

typedef short bf16x8 __attribute__((ext_vector_type(8)));
typedef unsigned short u16x8 __attribute__((ext_vector_type(8)));
typedef float f32x4 __attribute__((ext_vector_type(4)));

#define NPB 512          // nodes per bucket
#define BSHIFT 9
#define MAXBUCK 256      // supports N <= 131072
#define STAGE_CAP 12288  // per-bucket csr staging (mean 8163, sigma ~90)
#define LROW 136         // LDS mean row stride in shorts (272 B)
#define BINWIN 8192      // edges per bin_kernel block

__device__ __forceinline__ short f2bf(float f) {
    uint32_t u = __float_as_uint(f);
    u += 0x7fffu + ((u >> 16) & 1u);   // round-to-nearest-even
    return (short)(u >> 16);
}
__device__ __forceinline__ float bf2f(unsigned short s) {
    return __uint_as_float((uint32_t)s << 16);
}

// ---- prep: convx (f32->bf16) || convw4 || coarse bucket histogram ----
__global__ __launch_bounds__(256) void prep_kernel(
    const float* __restrict__ x, short* __restrict__ xb, int nx,
    const float* __restrict__ w0, const float* __restrict__ w1,
    const float* __restrict__ w2, const float* __restrict__ w3,
    short* __restrict__ o0, short* __restrict__ o1,
    short* __restrict__ o2, short* __restrict__ o3,
    const int* __restrict__ dst, int* __restrict__ bcnt, int E, int B,
    int cxBlocks, int histBlocks)
{
    int b = blockIdx.x;
    if (b < cxBlocks) {                       // ---- convx
        int i = (b * 256 + threadIdx.x) * 8;
        if (i + 8 <= nx) {
            const float4 v0 = *(const float4*)(x + i);
            const float4 v1 = *(const float4*)(x + i + 4);
            bf16x8 o;
            o[0] = f2bf(v0.x); o[1] = f2bf(v0.y); o[2] = f2bf(v0.z); o[3] = f2bf(v0.w);
            o[4] = f2bf(v1.x); o[5] = f2bf(v1.y); o[6] = f2bf(v1.z); o[7] = f2bf(v1.w);
            *(bf16x8*)(xb + i) = o;
        } else {
            for (int j = i; j < nx; ++j) xb[j] = f2bf(x[j]);
        }
        return;
    }
    b -= cxBlocks;
    if (b < 64) {                             // ---- convw4 (4x 16384 elems)
        int i = b * 256 + threadIdx.x;
        o0[i] = f2bf(w0[i]);
        o1[i] = f2bf(w1[i]);
        o2[i] = f2bf(w2[i]);
        o3[i] = f2bf(w3[i]);
        return;
    }
    b -= 64;                                  // ---- bucket histogram (LDS-agg)
    __shared__ int h[MAXBUCK];
    for (int i = threadIdx.x; i < B; i += 256) h[i] = 0;
    __syncthreads();
    const int stride = histBlocks * 256;
    for (int e = b * 256 + threadIdx.x; e < E; e += stride)
        atomicAdd(&h[dst[e] >> BSHIFT], 1);
    __syncthreads();
    for (int i = threadIdx.x; i < B; i += 256)
        if (h[i]) atomicAdd(&bcnt[i], h[i]);
}

// ---- scan bucket counts -> bases + init cursors; rowptr[N]=E ----
__global__ __launch_bounds__(256) void bscan_kernel(const int* __restrict__ bcnt,
                                                    int* __restrict__ bbase,
                                                    int* __restrict__ gcur,
                                                    int* __restrict__ rowptr,
                                                    int E, int N, int B) {
    __shared__ int s[256];
    int t = threadIdx.x;
    int v = (t < B) ? bcnt[t] : 0;
    s[t] = v;
    __syncthreads();
    for (int off = 1; off < 256; off <<= 1) {
        int a = (t >= off) ? s[t - off] : 0;
        __syncthreads();
        s[t] += a;
        __syncthreads();
    }
    int excl = s[t] - v;
    if (t < B) { bbase[t] = excl; gcur[t] = excl; }
    if (t == B - 1) bbase[B] = excl + v;
    if (t == 0) rowptr[N] = E;
}

// ---- bin edges into bucket regions as packed records (src<<9 | dst&511) ----
// R10 PMC: direct interleaved 4B scatters amplified binned writes ~4x
// (WRITE_SIZE 44MB vs 26MB payload). Fix: counting-sort the window into LDS
// (records grouped by bucket), then each WAVE writes one bucket's run with
// 64-wide contiguous stores — full-line bursts.
__global__ __launch_bounds__(512) void bin_kernel(const int* __restrict__ src,
                                                  const int* __restrict__ dst,
                                                  int* __restrict__ gcur,
                                                  unsigned int* __restrict__ binned,
                                                  int E, int B) {
    __shared__ int cnt[MAXBUCK];
    __shared__ int gbase[MAXBUCK];
    __shared__ int lbase[MAXBUCK];
    __shared__ int lcur[MAXBUCK];
    __shared__ int ws[512];
    __shared__ unsigned int stage[BINWIN];
    const int t = threadIdx.x;
    for (int i = t; i < B; i += 512) cnt[i] = 0;
    __syncthreads();
    const int e0 = blockIdx.x * BINWIN;
    const int eEnd = (e0 + BINWIN < E) ? (e0 + BINWIN) : E;
#pragma unroll 4
    for (int e = e0 + t; e < eEnd; e += 512)
        atomicAdd(&cnt[dst[e] >> BSHIFT], 1);
    __syncthreads();
    // exclusive scan of cnt -> lbase (position of each bucket's run in stage)
    const int v = (t < B) ? cnt[t] : 0;
    ws[t] = v;
    __syncthreads();
    for (int off = 1; off < 512; off <<= 1) {
        int a = (t >= off) ? ws[t - off] : 0;
        __syncthreads();
        ws[t] += a;
        __syncthreads();
    }
    if (t < B) {
        const int excl = ws[t] - v;
        lbase[t] = excl;
        lcur[t]  = excl;
        gbase[t] = v ? atomicAdd(&gcur[t], v) : 0;
    }
    __syncthreads();
    // stage records grouped by bucket (LDS counting sort)
#pragma unroll 4
    for (int e = e0 + t; e < eEnd; e += 512) {
        int sv = src[e], dv = dst[e];
        int b = dv >> BSHIFT;
        int pos = atomicAdd(&lcur[b], 1);
        stage[pos] = ((unsigned)sv << BSHIFT) | (unsigned)(dv & (NPB - 1));
    }
    __syncthreads();
    // per-wave coalesced group writes
    const int wv = t >> 6, ln = t & 63;
    for (int b = wv; b < B; b += 8) {
        const int c = cnt[b];
        if (!c) continue;
        const int lb = lbase[b], gb = gbase[b];
        for (int i = ln; i < c; i += 64)
            binned[gb + i] = stage[lb + i];
    }
}

// ---- per-bucket: local hist + scan -> rowptr; LDS scatter -> coalesced csr ----
__global__ __launch_bounds__(512) void build_kernel(const unsigned int* __restrict__ binned,
                                                    const int* __restrict__ bbase,
                                                    int* __restrict__ rowptr,
                                                    int* __restrict__ csr, int N) {
    __shared__ int hist[NPB];
    __shared__ int cur[NPB];
    __shared__ int scanb[NPB];
    __shared__ int stage[STAGE_CAP];
    const int b = blockIdx.x;
    const int t = threadIdx.x;      // 0..511 == NPB
    const int cbeg = bbase[b], cend = bbase[b + 1];
    const int cnt = cend - cbeg;
    hist[t] = 0;
    __syncthreads();
    for (int i = t; i < cnt; i += 512)
        atomicAdd(&hist[binned[cbeg + i] & (NPB - 1)], 1);
    __syncthreads();
    const int ps = hist[t];
    scanb[t] = ps;
    __syncthreads();
    for (int off = 1; off < 512; off <<= 1) {
        int a = (t >= off) ? scanb[t - off] : 0;
        __syncthreads();
        scanb[t] += a;
        __syncthreads();
    }
    const int e0 = scanb[t] - ps;   // exclusive prefix over 512 nodes
    cur[t] = e0;
    const int node = (b << BSHIFT) + t;
    if (node < N) rowptr[node] = cbeg + e0;
    __syncthreads();
    for (int i = t; i < cnt; i += 512) {
        unsigned rec = binned[cbeg + i];
        int ld  = rec & (NPB - 1);
        int pos = atomicAdd(&cur[ld], 1);
        if (pos < STAGE_CAP) stage[pos] = (int)(rec >> BSHIFT);
        else                 csr[cbeg + pos] = (int)(rec >> BSHIFT);
    }
    __syncthreads();
    const int lim = cnt < STAGE_CAP ? cnt : STAGE_CAP;
    for (int i = t; i < lim; i += 512)
        csr[cbeg + i] = stage[i];
}

// ---- fused layer: out = [relu]( mean(feat) @ Wl^T + b + feat @ Wr^T ) ----
// R3 geometry (measured 124.4 us, 44 VGPR, 45% occ — best of 4 variants):
// block = 4 waves = 32 nodes; quarter-wave owns 2 nodes; phase 2 splits each
// 16-row MFMA tile across 2 waves (4 column-tiles each); one __syncthreads.
#define ACC8(u) do { \
    a0 += bf2f(u[0]); a1 += bf2f(u[1]); a2 += bf2f(u[2]); a3 += bf2f(u[3]); \
    a4 += bf2f(u[4]); a5 += bf2f(u[5]); a6 += bf2f(u[6]); a7 += bf2f(u[7]); } while (0)

template <bool RELU>
__global__ __launch_bounds__(256) void fused_kernel(
    const short* __restrict__ feat, const int* __restrict__ csr,
    const int* __restrict__ rowptr,
    const short* __restrict__ Wl, const short* __restrict__ Wr,
    const float* __restrict__ bias,
    short* __restrict__ outb, float* __restrict__ outf, int N)
{
    __shared__ short lmean[32 * LROW];
    const int lane = threadIdx.x & 63;
    const int wave = threadIdx.x >> 6;
    const int q    = lane >> 4;          // quarter
    const int ql   = lane & 15;          // lane in quarter
    const int nb0  = blockIdx.x * 32;    // block's first node
    const int m0w  = nb0 + wave * 8;     // wave's first node (phase 1)

    // ---- phase 1: aggregate; quarter q owns node m0w + it*4 + q (it=0,1)
    for (int it = 0; it < 2; ++it) {
        const int node = m0w + it * 4 + q;
        const int lrow = wave * 8 + it * 4 + q;
        float a0=0,a1=0,a2=0,a3=0,a4=0,a5=0,a6=0,a7=0;
        if (node < N) {
            const int beg = rowptr[node], end = rowptr[node + 1];
            int e = beg;
            for (; e + 4 <= end; e += 4) {
                const int s0 = csr[e], s1 = csr[e+1], s2 = csr[e+2], s3 = csr[e+3];
                const u16x8 u0 = *(const u16x8*)(feat + (size_t)s0 * 128 + ql * 8);
                const u16x8 u1 = *(const u16x8*)(feat + (size_t)s1 * 128 + ql * 8);
                const u16x8 u2 = *(const u16x8*)(feat + (size_t)s2 * 128 + ql * 8);
                const u16x8 u3 = *(const u16x8*)(feat + (size_t)s3 * 128 + ql * 8);
                ACC8(u0); ACC8(u1); ACC8(u2); ACC8(u3);
            }
            for (; e < end; ++e) {
                const u16x8 u = *(const u16x8*)(feat + (size_t)csr[e] * 128 + ql * 8);
                ACC8(u);
            }
            const float r = 1.0f / fmaxf((float)(end - beg), 1.0f);
            bf16x8 o;
            o[0] = f2bf(a0 * r); o[1] = f2bf(a1 * r); o[2] = f2bf(a2 * r); o[3] = f2bf(a3 * r);
            o[4] = f2bf(a4 * r); o[5] = f2bf(a5 * r); o[6] = f2bf(a6 * r); o[7] = f2bf(a7 * r);
            *(bf16x8*)(lmean + (size_t)lrow * LROW + ql * 8) = o;
        } else {
            *(bf16x8*)(lmean + (size_t)lrow * LROW + ql * 8) = (bf16x8)0;
        }
    }
    __syncthreads();   // phase 2 reads lmean rows written by a sibling wave

    // ---- phase 2: wave -> (row-tile t2 = wave>>1, col-half h = wave&1)
    const int t2 = wave >> 1;
    const int h  = wave & 1;
    const int m0 = nb0 + t2 * 16;        // tile's first node row
    f32x4 acc[4];
#pragma unroll
    for (int i = 0; i < 4; ++i) acc[i] = (f32x4)0.0f;
    const bool valid = (m0 + ql < N);

#pragma unroll
    for (int kk = 0; kk < 4; ++kk) {
        const int kb = kk * 32 + q * 8;
        const bf16x8 a = *(const bf16x8*)(lmean + (size_t)(t2 * 16 + ql) * LROW + kb);
#pragma unroll
        for (int nt = 0; nt < 4; ++nt) {
            const bf16x8 b = *(const bf16x8*)(Wl + (size_t)(h * 64 + nt * 16 + ql) * 128 + kb);
            acc[nt] = __builtin_amdgcn_mfma_f32_16x16x32_bf16(a, b, acc[nt], 0, 0, 0);
        }
    }
#pragma unroll
    for (int kk = 0; kk < 4; ++kk) {
        const int kb = kk * 32 + q * 8;
        bf16x8 a = (bf16x8)0;
        if (valid) a = *(const bf16x8*)(feat + (size_t)(m0 + ql) * 128 + kb);
#pragma unroll
        for (int nt = 0; nt < 4; ++nt) {
            const bf16x8 b = *(const bf16x8*)(Wr + (size_t)(h * 64 + nt * 16 + ql) * 128 + kb);
            acc[nt] = __builtin_amdgcn_mfma_f32_16x16x32_bf16(a, b, acc[nt], 0, 0, 0);
        }
    }

    const int rbase = m0 + q * 4;
#pragma unroll
    for (int nt = 0; nt < 4; ++nt) {
        const int col = h * 64 + nt * 16 + ql;
        const float bc = bias[col];
#pragma unroll
        for (int r = 0; r < 4; ++r) {
            const int node = rbase + r;
            if (node < N) {
                float v = acc[nt][r] + bc;
                if (RELU) outb[(size_t)node * 128 + col] = f2bf(fmaxf(v, 0.0f));
                else      outf[(size_t)node * 128 + col] = v;
            }
        }
    }
}

extern "C" void kernel_launch(void* const* d_in, const int* in_sizes, int n_in,
                              void* d_out, int out_size, void* d_ws, size_t ws_size,
                              hipStream_t stream) {
    const float* x   = (const float*)d_in[0];
    const int*   ei  = (const int*)d_in[1];
    const float* Wl1 = (const float*)d_in[2];
    const float* bl1 = (const float*)d_in[3];
    const float* Wr1 = (const float*)d_in[4];
    const float* Wl2 = (const float*)d_in[5];
    const float* bl2 = (const float*)d_in[6];
    const float* Wr2 = (const float*)d_in[7];

    const int N = in_sizes[0] / 128;
    const int E = in_sizes[1] / 2;
    const int* src = ei;
    const int* dst = ei + E;
    const int B = (N + NPB - 1) >> BSHIFT;   // 196 for N=100000

    // ws: h_bf16 | 4x bf16 weights | rowptr | csr | binned | bucket meta (~39 MB)
    char* wsb = (char*)d_ws;
    short* hbuf = (short*)wsb;                                  // N*128 bf16
    size_t off = (size_t)N * 128 * 2;
    short* wl1 = (short*)(wsb + off); off += 16384 * 2;
    short* wr1 = (short*)(wsb + off); off += 16384 * 2;
    short* wl2 = (short*)(wsb + off); off += 16384 * 2;
    short* wr2 = (short*)(wsb + off); off += 16384 * 2;
    int* rowptr = (int*)(wsb + off);                            // N+1
    off += ((size_t)(N + 1) * 4 + 15) & ~(size_t)15;
    int* csr = (int*)(wsb + off);                               // E
    off += ((size_t)E * 4 + 15) & ~(size_t)15;
    unsigned int* binned = (unsigned int*)(wsb + off);          // E
    off += ((size_t)E * 4 + 15) & ~(size_t)15;
    int* bcnt  = (int*)(wsb + off);                             // MAXBUCK+1
    int* bbase = bcnt + (MAXBUCK + 1);                          // MAXBUCK+1
    int* gcur  = bbase + (MAXBUCK + 1);                         // MAXBUCK

    // d_out: xb (bf16 x) at base — read only by fused1, overwritten by fused2's out
    short* xb  = (short*)d_out;
    float* out = (float*)d_out;

    const int nx = N * 128;
    const int cxBlocks    = (nx / 8 + 255) / 256;   // 6250
    const int histBlocks  = 1024;
    const int binBlocks   = (E + BINWIN - 1) / BINWIN;
    const int fusedBlocks = (N + 31) / 32;

    (void)hipMemsetAsync(bcnt, 0, (size_t)(MAXBUCK + 1) * sizeof(int), stream);

    // convx || convw4 || bucket histogram, one full-GPU launch
    prep_kernel<<<cxBlocks + 64 + histBlocks, 256, 0, stream>>>(
        x, xb, nx, Wl1, Wr1, Wl2, Wr2, wl1, wr1, wl2, wr2,
        dst, bcnt, E, B, cxBlocks, histBlocks);
    bscan_kernel<<<1, 256, 0, stream>>>(bcnt, bbase, gcur, rowptr, E, N, B);
    bin_kernel<<<binBlocks, 512, 0, stream>>>(src, dst, gcur, binned, E, B);
    build_kernel<<<B, 512, 0, stream>>>(binned, bbase, rowptr, csr, N);

    // layer 1: feat = xb (d_out), out = hbuf (ws)
    fused_kernel<true><<<fusedBlocks, 256, 0, stream>>>(xb, csr, rowptr, wl1, wr1, bl1,
                                                        hbuf, (float*)nullptr, N);
    // layer 2: feat = hbuf (ws), out = d_out (overwrites xb region; safe)
    fused_kernel<false><<<fusedBlocks, 256, 0, stream>>>(hbuf, csr, rowptr, wl2, wr2, bl2,
                                                         (short*)nullptr, out, N);
}